// Round 2
// baseline (2007.954 us; speedup 1.0000x reference)
//
#include <hip/hip_runtime.h>

#define LEAKF (1.0f/3.0f)
#define BN_EPS 1e-4f

// ---------------- hash table (open addressing, linear probe) ----------------
__device__ __forceinline__ unsigned hmix(int key) {
    unsigned h = (unsigned)key * 2654435761u;
    h ^= h >> 15;
    return h;
}

__device__ __forceinline__ int hlookup(const int* __restrict__ hk,
                                       const int* __restrict__ hv,
                                       int mask, int key) {
    unsigned h = hmix(key) & (unsigned)mask;
    while (true) {
        int k = hk[h];
        if (k == key) return hv[h];
        if (k == -1) return -1;
        h = (h + 1) & (unsigned)mask;
    }
}

__global__ void build_hash(const int* __restrict__ coords, int N, int S,
                           int* __restrict__ hk, int* __restrict__ hv, int mask) {
    int i = blockIdx.x * blockDim.x + threadIdx.x;
    if (i >= N) return;
    int key = (coords[3 * i] * S + coords[3 * i + 1]) * S + coords[3 * i + 2];
    unsigned h = hmix(key) & (unsigned)mask;
    while (true) {
        int old = atomicCAS(&hk[h], -1, key);
        if (old == -1 || old == key) { hv[h] = i; break; }
        h = (h + 1) & (unsigned)mask;
    }
}

// ---------------- initial 7x7x7 conv, Cin=1, Cout=64 ----------------
__global__ __launch_bounds__(64) void conv_init_kernel(
    int M, const int* __restrict__ oc,
    const float* __restrict__ f0, const float* __restrict__ W,
    float* __restrict__ outF,
    const int* __restrict__ hk, const int* __restrict__ hv, int mask) {
    __shared__ int sIdx[343];
    __shared__ int sK[343];
    __shared__ int sCount;
    int m = blockIdx.x, tid = threadIdx.x;
    int cx = oc[3 * m], cy = oc[3 * m + 1], cz = oc[3 * m + 2];
    if (tid == 0) sCount = 0;
    __syncthreads();
    for (int k = tid; k < 343; k += 64) {
        int a = k / 49, rem = k - a * 49, b = rem / 7, c = rem - b * 7;
        int x = cx + a - 3, y = cy + b - 3, z = cz + c - 3;
        if ((unsigned)x < 512u && (unsigned)y < 512u && (unsigned)z < 512u) {
            int idx = hlookup(hk, hv, mask, (x * 512 + y) * 512 + z);
            if (idx >= 0) { int p = atomicAdd(&sCount, 1); sIdx[p] = idx; sK[p] = k; }
        }
    }
    __syncthreads();
    int cnt = sCount;
    float acc = 0.f;
    for (int j = 0; j < cnt; j++) {
        acc += f0[sIdx[j]] * W[sK[j] * 64 + tid];
    }
    outF[(size_t)m * 64 + tid] = acc;
}

// ---------------- generic gather conv ----------------
// out[m, co] = sum over found offsets k: inF[idx(k), :] . W[k, :, co]
template <int CIN, int COUT, int RANGE, int ROFF, int STRIDE>
__global__ __launch_bounds__(COUT) void conv_gather(
    int M, const int* __restrict__ oc, const float* __restrict__ inF,
    const float* __restrict__ W, float* __restrict__ outF,
    const int* __restrict__ hk, const int* __restrict__ hv, int mask, int Sin) {
    constexpr int K3 = RANGE * RANGE * RANGE;
    __shared__ float sF[CIN];
    __shared__ int sIdx[K3];
    __shared__ int sK[K3];
    __shared__ int sCount;
    int m = blockIdx.x, tid = threadIdx.x;
    int cx = oc[3 * m], cy = oc[3 * m + 1], cz = oc[3 * m + 2];
    if (tid == 0) sCount = 0;
    __syncthreads();
    for (int k = tid; k < K3; k += COUT) {
        int a = k / (RANGE * RANGE), rem = k - a * RANGE * RANGE;
        int b = rem / RANGE, c = rem - b * RANGE;
        int x = cx * STRIDE + a - ROFF;
        int y = cy * STRIDE + b - ROFF;
        int z = cz * STRIDE + c - ROFF;
        if ((unsigned)x < (unsigned)Sin && (unsigned)y < (unsigned)Sin &&
            (unsigned)z < (unsigned)Sin) {
            int key = (x * Sin + y) * Sin + z;
            int idx = hlookup(hk, hv, mask, key);
            if (idx >= 0) { int p = atomicAdd(&sCount, 1); sIdx[p] = idx; sK[p] = k; }
        }
    }
    __syncthreads();
    int cnt = sCount;
    float acc = 0.f;
    for (int j = 0; j < cnt; j++) {
        int idx = sIdx[j], k = sK[j];
        __syncthreads();  // protect sF from previous iteration's readers
        for (int ci = tid; ci < CIN; ci += COUT) sF[ci] = inF[(size_t)idx * CIN + ci];
        __syncthreads();
        const float* wk = W + (size_t)k * CIN * COUT + tid;
#pragma unroll 8
        for (int ci = 0; ci < CIN; ci++) acc += sF[ci] * wk[(size_t)ci * COUT];
    }
    outF[(size_t)m * COUT + tid] = acc;
}

// ---------------- final 4x down conv, Cin=64, Cout=2 ----------------
__global__ __launch_bounds__(64) void convd4_kernel(
    int M, const int* __restrict__ oc, const float* __restrict__ x3,
    const float* __restrict__ W, float* __restrict__ out4,
    const int* __restrict__ hk, const int* __restrict__ hv, int mask) {
    __shared__ int sIdx[64];
    __shared__ int sK[64];
    __shared__ int sCount;
    int m = blockIdx.x, tid = threadIdx.x;
    int cx = oc[3 * m], cy = oc[3 * m + 1], cz = oc[3 * m + 2];
    if (tid == 0) sCount = 0;
    __syncthreads();
    {
        int k = tid;
        int a = k >> 4, b = (k >> 2) & 3, c = k & 3;
        int x = cx * 4 + a, y = cy * 4 + b, z = cz * 4 + c;
        int key = (x * 32 + y) * 32 + z;
        int idx = hlookup(hk, hv, mask, key);
        if (idx >= 0) { int p = atomicAdd(&sCount, 1); sIdx[p] = idx; sK[p] = k; }
    }
    __syncthreads();
    int cnt = sCount;
    float a0 = 0.f, a1 = 0.f;
    for (int j = 0; j < cnt; j++) {
        int idx = sIdx[j], k = sK[j];
        float f = x3[(size_t)idx * 64 + tid];
        const float* wk = W + ((size_t)k * 64 + tid) * 2;
        a0 += f * wk[0];
        a1 += f * wk[1];
    }
    for (int o = 32; o > 0; o >>= 1) {
        a0 += __shfl_down(a0, o);
        a1 += __shfl_down(a1, o);
    }
    if (tid == 0) { out4[2 * m] = a0; out4[2 * m + 1] = a1; }
}

// ---------------- batchnorm: partial sums ----------------
__global__ __launch_bounds__(256) void bn_reduce(const float* __restrict__ X, int total,
                                                 int Cmask, float* __restrict__ sums, int C) {
    __shared__ float sS[128];
    __shared__ float sQ[128];
    int tid = threadIdx.x;
    if (tid < C) { sS[tid] = 0.f; sQ[tid] = 0.f; }
    __syncthreads();
    int base = blockIdx.x * 128 * C;
    int end = base + 128 * C;
    if (end > total) end = total;
    for (int e = base + tid; e < end; e += 256) {
        float v = X[e];
        int c = e & Cmask;
        atomicAdd(&sS[c], v);
        atomicAdd(&sQ[c], v * v);
    }
    __syncthreads();
    if (tid < C) {
        atomicAdd(&sums[tid], sS[tid]);
        atomicAdd(&sums[128 + tid], sQ[tid]);
    }
}

__global__ void bn_finalize(const float* __restrict__ sums,
                            const float* __restrict__ g,
                            const float* __restrict__ b,
                            float invN, int C, float* __restrict__ sc, float* __restrict__ sh) {
    int c = threadIdx.x;
    if (c < C) {
        float mean = sums[c] * invN;
        float var = sums[128 + c] * invN - mean * mean;
        float s = g[c] / sqrtf(var + BN_EPS);
        sc[c] = s;
        sh[c] = b[c] - mean * s;
    }
}

__global__ __launch_bounds__(256) void bn_apply(const float* __restrict__ X, float* __restrict__ Y,
                                                int total, int Cmask,
                                                const float* __restrict__ sc,
                                                const float* __restrict__ sh) {
    int e = blockIdx.x * 256 + threadIdx.x;
    if (e >= total) return;
    int c = e & Cmask;
    float v = X[e] * sc[c] + sh[c];
    Y[e] = v > 0.f ? v : v * LEAKF;
}

__global__ __launch_bounds__(256) void add_lrelu(const float* __restrict__ A,
                                                 const float* __restrict__ R,
                                                 float* __restrict__ Y, int total) {
    int e = blockIdx.x * 256 + threadIdx.x;
    if (e >= total) return;
    float v = A[e] + R[e];
    Y[e] = v > 0.f ? v : v * LEAKF;
}

// ---------------- bn + scatter to dense [512,2] ----------------
__global__ __launch_bounds__(256) void bn_scatter(int M, const int* __restrict__ c4,
                                                  const float* __restrict__ x4,
                                                  const float* __restrict__ sc,
                                                  const float* __restrict__ sh,
                                                  float* __restrict__ dense) {
    int i = blockIdx.x * 256 + threadIdx.x;
    if (i >= 2 * M) return;
    int m = i >> 1, co = i & 1;
    float v = x4[i] * sc[co] + sh[co];
    v = v > 0.f ? v : v * LEAKF;
    int key = (c4[3 * m] * 8 + c4[3 * m + 1]) * 8 + c4[3 * m + 2];
    dense[key * 2 + co] = v;
}

// ---------------- head: flat[1,1024] @ W2 -> elu -> @ W3 -> sigmoid ----------------
__global__ __launch_bounds__(256) void head_kernel(const float* __restrict__ dense,
                                                   const float* __restrict__ W2,
                                                   const float* __restrict__ b2,
                                                   const float* __restrict__ W3,
                                                   const float* __restrict__ b3,
                                                   float* __restrict__ out) {
    __shared__ float r0[256];
    __shared__ float r1[256];
    int tid = threadIdx.x;
    float a0 = 0.f, a1 = 0.f;
    for (int j = tid; j < 1024; j += 256) {
        int co = j >> 9, k = j & 511;  // flat[j] = dense[k][co] (channel-major flatten)
        float f = dense[k * 2 + co];
        a0 += f * W2[2 * j];
        a1 += f * W2[2 * j + 1];
    }
    r0[tid] = a0;
    r1[tid] = a1;
    __syncthreads();
    for (int s = 128; s > 0; s >>= 1) {
        if (tid < s) { r0[tid] += r0[tid + s]; r1[tid] += r1[tid + s]; }
        __syncthreads();
    }
    if (tid == 0) {
        float v0 = r0[0] + b2[0];
        float v1 = r1[0] + b2[1];
        v0 = v0 > 0.f ? v0 : expm1f(v0);
        v1 = v1 > 0.f ? v1 : expm1f(v1);
        float z = v0 * W3[0] + v1 * W3[1] + b3[0];
        out[0] = 1.f / (1.f + expf(-z));
    }
}

// ---------------- host ----------------
extern "C" void kernel_launch(void* const* d_in, const int* in_sizes, int n_in,
                              void* d_out, int out_size, void* d_ws, size_t ws_size,
                              hipStream_t stream) {
    const float* F0    = (const float*)d_in[0];
    const float* Winit = (const float*)d_in[1];
    const float* Wd1   = (const float*)d_in[2];
    const float* gd1   = (const float*)d_in[3];
    const float* bd1   = (const float*)d_in[4];
    const float* W11a  = (const float*)d_in[5];
    const float* g11   = (const float*)d_in[6];
    const float* b11   = (const float*)d_in[7];
    const float* W11b  = (const float*)d_in[8];
    const float* W12a  = (const float*)d_in[9];
    const float* g12   = (const float*)d_in[10];
    const float* b12   = (const float*)d_in[11];
    const float* W12b  = (const float*)d_in[12];
    const float* Wd2   = (const float*)d_in[13];
    const float* gd2   = (const float*)d_in[14];
    const float* bd2   = (const float*)d_in[15];
    const float* W21a  = (const float*)d_in[16];
    const float* g21   = (const float*)d_in[17];
    const float* b21   = (const float*)d_in[18];
    const float* W21b  = (const float*)d_in[19];
    const float* W22a  = (const float*)d_in[20];
    const float* g22   = (const float*)d_in[21];
    const float* b22   = (const float*)d_in[22];
    const float* W22b  = (const float*)d_in[23];
    const float* Wd3   = (const float*)d_in[24];
    const float* gd3   = (const float*)d_in[25];
    const float* bd3   = (const float*)d_in[26];
    const float* Wd4   = (const float*)d_in[27];
    const float* gd4   = (const float*)d_in[28];
    const float* bd4   = (const float*)d_in[29];
    const float* W2    = (const float*)d_in[30];
    const float* b2    = (const float*)d_in[31];
    const float* W3    = (const float*)d_in[32];
    const float* b3    = (const float*)d_in[33];
    const int* c0 = (const int*)d_in[34];
    const int* c1 = (const int*)d_in[35];
    const int* c2 = (const int*)d_in[36];
    const int* c3 = (const int*)d_in[37];
    const int* c4 = (const int*)d_in[38];
    int N0 = in_sizes[34] / 3, N1 = in_sizes[35] / 3, N2 = in_sizes[36] / 3;
    int N3 = in_sizes[37] / 3, N4 = in_sizes[38] / 3;

    // ---- workspace layout ----
    char* base = (char*)d_ws;
    size_t off = 0;
    auto alloc = [&](size_t bytes) -> void* {
        void* p = base + off;
        off = (off + bytes + 255) & ~(size_t)255;
        return p;
    };
    const int CAP = 131072, CAP3 = 65536;
    int* hk0 = (int*)alloc((size_t)CAP * 4);
    int* hv0 = (int*)alloc((size_t)CAP * 4);
    int* hk1 = (int*)alloc((size_t)CAP * 4);
    int* hv1 = (int*)alloc((size_t)CAP * 4);
    int* hk2 = (int*)alloc((size_t)CAP * 4);
    int* hv2 = (int*)alloc((size_t)CAP * 4);
    int* hk3 = (int*)alloc((size_t)CAP3 * 4);
    int* hv3 = (int*)alloc((size_t)CAP3 * 4);
    float* sums = (float*)alloc(256 * 4);
    float* sc = (float*)alloc(128 * 4);
    float* sh = (float*)alloc(128 * 4);
    float* dense = (float*)alloc(1024 * 4);
    float* x4 = (float*)alloc((size_t)N4 * 2 * 4);
    size_t relems = (size_t)N0 * 64;
    if ((size_t)N2 * 128 > relems) relems = (size_t)N2 * 128;
    float* R1 = (float*)alloc(relems * 4);
    float* R2 = (float*)alloc(relems * 4);
    float* R3 = (float*)alloc(relems * 4);

    // ---- hash tables (ws is re-poisoned each call; rebuild every call) ----
    hipMemsetAsync(hk0, 0xFF, (size_t)CAP * 4, stream);
    hipMemsetAsync(hk1, 0xFF, (size_t)CAP * 4, stream);
    hipMemsetAsync(hk2, 0xFF, (size_t)CAP * 4, stream);
    hipMemsetAsync(hk3, 0xFF, (size_t)CAP3 * 4, stream);
    build_hash<<<(N0 + 255) / 256, 256, 0, stream>>>(c0, N0, 512, hk0, hv0, CAP - 1);
    build_hash<<<(N1 + 255) / 256, 256, 0, stream>>>(c1, N1, 256, hk1, hv1, CAP - 1);
    build_hash<<<(N2 + 255) / 256, 256, 0, stream>>>(c2, N2, 128, hk2, hv2, CAP - 1);
    build_hash<<<(N3 + 255) / 256, 256, 0, stream>>>(c3, N3, 32, hk3, hv3, CAP3 - 1);

    auto bn = [&](const float* X, float* Y, int N, int C,
                  const float* g, const float* b) {
        hipMemsetAsync(sums, 0, 256 * 4, stream);
        int total = N * C;
        bn_reduce<<<(N + 127) / 128, 256, 0, stream>>>(X, total, C - 1, sums, C);
        bn_finalize<<<1, 128, 0, stream>>>(sums, g, b, 1.0f / (float)N, C, sc, sh);
        bn_apply<<<(total + 255) / 256, 256, 0, stream>>>(X, Y, total, C - 1, sc, sh);
    };

    // ---- initial conv @512, 7^3, Cin=1 -> Cout=64 : R3 ----
    conv_init_kernel<<<N0, 64, 0, stream>>>(N0, c0, F0, Winit, R3, hk0, hv0, CAP - 1);

    // ---- down1 (stride 2, 2^3): R3[N0,64] -> R1[N1,64]; bn -> R2 = x1 ----
    conv_gather<64, 64, 2, 0, 2><<<N1, 64, 0, stream>>>(N1, c1, R3, Wd1, R1, hk0, hv0, CAP - 1, 512);
    bn(R1, R2, N1, 64, gd1, bd1);

    // ---- level-1 residual block 1 ----
    conv_gather<64, 64, 3, 1, 1><<<N1, 64, 0, stream>>>(N1, c1, R2, W11a, R1, hk1, hv1, CAP - 1, 256);
    bn(R1, R3, N1, 64, g11, b11);
    conv_gather<64, 64, 3, 1, 1><<<N1, 64, 0, stream>>>(N1, c1, R3, W11b, R1, hk1, hv1, CAP - 1, 256);
    add_lrelu<<<(N1 * 64 + 255) / 256, 256, 0, stream>>>(R1, R2, R2, N1 * 64);
    // ---- level-1 residual block 2 ----
    conv_gather<64, 64, 3, 1, 1><<<N1, 64, 0, stream>>>(N1, c1, R2, W12a, R1, hk1, hv1, CAP - 1, 256);
    bn(R1, R3, N1, 64, g12, b12);
    conv_gather<64, 64, 3, 1, 1><<<N1, 64, 0, stream>>>(N1, c1, R3, W12b, R1, hk1, hv1, CAP - 1, 256);
    add_lrelu<<<(N1 * 64 + 255) / 256, 256, 0, stream>>>(R1, R2, R2, N1 * 64);

    // ---- down2 (stride 2): R2[N1,64] -> R1[N2,128]; bn -> R3 = x2 ----
    conv_gather<64, 128, 2, 0, 2><<<N2, 128, 0, stream>>>(N2, c2, R2, Wd2, R1, hk1, hv1, CAP - 1, 256);
    bn(R1, R3, N2, 128, gd2, bd2);

    // ---- level-2 residual block 1 ----
    conv_gather<128, 128, 3, 1, 1><<<N2, 128, 0, stream>>>(N2, c2, R3, W21a, R1, hk2, hv2, CAP - 1, 128);
    bn(R1, R2, N2, 128, g21, b21);
    conv_gather<128, 128, 3, 1, 1><<<N2, 128, 0, stream>>>(N2, c2, R2, W21b, R1, hk2, hv2, CAP - 1, 128);
    add_lrelu<<<(N2 * 128 + 255) / 256, 256, 0, stream>>>(R1, R3, R3, N2 * 128);
    // ---- level-2 residual block 2 ----
    conv_gather<128, 128, 3, 1, 1><<<N2, 128, 0, stream>>>(N2, c2, R3, W22a, R1, hk2, hv2, CAP - 1, 128);
    bn(R1, R2, N2, 128, g22, b22);
    conv_gather<128, 128, 3, 1, 1><<<N2, 128, 0, stream>>>(N2, c2, R2, W22b, R1, hk2, hv2, CAP - 1, 128);
    add_lrelu<<<(N2 * 128 + 255) / 256, 256, 0, stream>>>(R1, R3, R3, N2 * 128);

    // ---- down3 (stride 4, 4^3): R3[N2,128] -> R1[N3,64]; bn -> R2 = x3 ----
    conv_gather<128, 64, 4, 0, 4><<<N3, 64, 0, stream>>>(N3, c3, R3, Wd3, R1, hk2, hv2, CAP - 1, 128);
    bn(R1, R2, N3, 64, gd3, bd3);

    // ---- down4 (stride 4): R2[N3,64] -> x4[N4,2]; bn + scatter -> dense[512,2] ----
    convd4_kernel<<<N4, 64, 0, stream>>>(N4, c4, R2, Wd4, x4, hk3, hv3, CAP3 - 1);
    hipMemsetAsync(sums, 0, 256 * 4, stream);
    bn_reduce<<<(N4 + 127) / 128, 256, 0, stream>>>(x4, N4 * 2, 1, sums, 2);
    bn_finalize<<<1, 128, 0, stream>>>(sums, gd4, bd4, 1.0f / (float)N4, 2, sc, sh);
    hipMemsetAsync(dense, 0, 1024 * 4, stream);
    bn_scatter<<<(2 * N4 + 255) / 256, 256, 0, stream>>>(N4, c4, x4, sc, sh, dense);

    // ---- head ----
    head_kernel<<<1, 256, 0, stream>>>(dense, W2, b2, W3, b3, (float*)d_out);
}